// Round 1
// baseline (183.334 us; speedup 1.0000x reference)
//
#include <hip/hip_runtime.h>
#include <stdint.h>

#define B_ 2
#define S_ 2048
#define D_ 1024
#define H_ 16
#define HD_ 64
#define K_ 64

typedef __attribute__((ext_vector_type(8))) __bf16 bf16x8v;
typedef __attribute__((ext_vector_type(4))) float f32x4;

#define GLD_LDS16(g, l)                                                        \
  __builtin_amdgcn_global_load_lds(                                            \
      (const __attribute__((address_space(1))) void*)(g),                      \
      (__attribute__((address_space(3))) void*)(l), 16, 0, 0)

__device__ __forceinline__ float bf2f(unsigned short u) {
  union { unsigned u32; float f; } c;
  c.u32 = ((unsigned)u) << 16;
  return c.f;
}
__device__ __forceinline__ unsigned short f2bf(float f) {
  union { float f; unsigned u; } c;
  c.f = f;
  unsigned u = c.u;
  u += 0x7fffu + ((u >> 16) & 1u);  // RNE (finite inputs)
  return (unsigned short)(u >> 16);
}

// ---------------- cast x (fp32 -> bf16), vectorized ----------------
__global__ __launch_bounds__(256) void cast_f32_bf16(
    const float4* __restrict__ in, ushort4* __restrict__ outp, int n4) {
  int i = blockIdx.x * 256 + threadIdx.x;
  if (i >= n4) return;
  float4 v = in[i];
  ushort4 o;
  o.x = f2bf(v.x); o.y = f2bf(v.y); o.z = f2bf(v.z); o.w = f2bf(v.w);
  outp[i] = o;
}

// ------------- transpose + cast weights: W (R x C) -> WT (C x R) bf16 -------------
__global__ __launch_bounds__(256) void transpose_cast(
    const float* __restrict__ W, unsigned short* __restrict__ WT, int R, int C) {
  __shared__ float tile[64][65];
  const int r0 = blockIdx.y * 64;
  const int c0 = blockIdx.x * 64;
  const int t = threadIdx.x;
#pragma unroll
  for (int i = 0; i < 16; ++i) {
    int idx = t + i * 256;
    int rr = idx >> 6, cc = idx & 63;
    tile[rr][cc] = W[(size_t)(r0 + rr) * C + c0 + cc];
  }
  __syncthreads();
#pragma unroll
  for (int i = 0; i < 16; ++i) {
    int idx = t + i * 256;
    int rr = idx >> 6, cc = idx & 63;  // rr: row of WT (= col of W)
    WT[(size_t)(c0 + rr) * R + r0 + cc] = f2bf(tile[cc][rr]);
  }
}

// ---------------- bf16 GEMM, 128x128 tile, m97 structure ----------------
// A: M x Kd row-major (bf16 bits), Bt: N x Kd row-major (B transposed, bf16 bits)
// C = A @ B + bias;  OUT_F32 ? fp32 out : bf16 out
template <bool OUT_F32>
__global__ __launch_bounds__(256) void gemm_bias(
    const unsigned short* __restrict__ A, const unsigned short* __restrict__ Bt,
    const float* __restrict__ bias, void* __restrict__ Cout,
    int M, int N, int Kd) {
  __shared__ unsigned short As[128 * 32];
  __shared__ unsigned short Bs[128 * 32];
  const int t = threadIdx.x;
  const int w = t >> 6;
  const int l = t & 63;
  const int m0 = blockIdx.y * 128;
  const int n0 = blockIdx.x * 128;
  const int wr = w >> 1, wc = w & 1;

  f32x4 acc[4][4] = {};

  const int srow = t >> 2;          // 0..63
  const int scol = (t & 3) * 8;     // 0,8,16,24
  char* asBase = (char*)As + w * 1024;
  char* bsBase = (char*)Bs + w * 1024;

  const int lr = l & 15;
  const int kh = (l >> 4) * 8;

  const int KT = Kd >> 5;
  for (int kt = 0; kt < KT; ++kt) {
    const int k0 = kt << 5;
    {
      const unsigned short* g0 = A + (size_t)(m0 + srow) * Kd + k0 + scol;
      const unsigned short* g1 = A + (size_t)(m0 + 64 + srow) * Kd + k0 + scol;
      GLD_LDS16(g0, asBase);
      GLD_LDS16(g1, asBase + 4096);
      const unsigned short* h0 = Bt + (size_t)(n0 + srow) * Kd + k0 + scol;
      const unsigned short* h1 = Bt + (size_t)(n0 + 64 + srow) * Kd + k0 + scol;
      GLD_LDS16(h0, bsBase);
      GLD_LDS16(h1, bsBase + 4096);
    }
    __syncthreads();  // drains vmcnt + lgkmcnt before barrier
    bf16x8v af[4], bfv[4];
#pragma unroll
    for (int m = 0; m < 4; ++m)
      af[m] = *(const bf16x8v*)&As[(wr * 64 + m * 16 + lr) * 32 + kh];
#pragma unroll
    for (int n = 0; n < 4; ++n)
      bfv[n] = *(const bf16x8v*)&Bs[(wc * 64 + n * 16 + lr) * 32 + kh];
#pragma unroll
    for (int m = 0; m < 4; ++m)
#pragma unroll
      for (int n = 0; n < 4; ++n)
        acc[m][n] = __builtin_amdgcn_mfma_f32_16x16x32_bf16(af[m], bfv[n],
                                                            acc[m][n], 0, 0, 0);
    __syncthreads();  // all waves done reading before next stage
  }

  const int rbase = (l >> 4) * 4;
#pragma unroll
  for (int m = 0; m < 4; ++m) {
#pragma unroll
    for (int n = 0; n < 4; ++n) {
      const int gc = n0 + wc * 64 + n * 16 + lr;
      const float bv = bias[gc];
#pragma unroll
      for (int j = 0; j < 4; ++j) {
        const int gr = m0 + wr * 64 + m * 16 + rbase + j;
        float v = acc[m][n][j] + bv;
        if (OUT_F32)
          ((float*)Cout)[(size_t)gr * N + gc] = v;
        else
          ((unsigned short*)Cout)[(size_t)gr * N + gc] = f2bf(v);
      }
    }
  }
}

// ---------------- routed gather attention ----------------
// qkv: (B*S) x 3072 bf16 bits, layout [q(1024)|k(1024)|v(1024)], head h at cols h*64..
// one block per (b,s); wave w owns heads 4w..4w+3 (cols w*256 .. +256)
__global__ __launch_bounds__(256) void attn_kernel(
    const unsigned short* __restrict__ qkv, const int* __restrict__ routes,
    unsigned short* __restrict__ outp) {
  __shared__ float sc[16][64];
  __shared__ int rts[64];
  const int bs = blockIdx.x;
  const int b = bs >> 11;       // / S_
  const int s = bs & (S_ - 1);
  const int t = threadIdx.x;
  const int w = t >> 6, l = t & 63;

  if (t < 64) {
    int r = routes[s * K_ + t];
    r = min(max(r, 0), S_ - 1);
    rts[t] = r;
  }
  __syncthreads();

  const int colo = w * 256 + l * 4;
  const int head = w * 4 + (l >> 4);
  const size_t rowbase = (size_t)bs * 3072;

  float q0, q1, q2, q3;
  {
    ushort4 u = *(const ushort4*)&qkv[rowbase + colo];
    q0 = bf2f(u.x); q1 = bf2f(u.y); q2 = bf2f(u.z); q3 = bf2f(u.w);
  }

  // scores
  for (int j = 0; j < K_; ++j) {
    const int r = rts[j];
    const size_t kb = ((size_t)(b * S_ + r)) * 3072 + 1024 + colo;
    ushort4 u = *(const ushort4*)&qkv[kb];
    float d = q0 * bf2f(u.x) + q1 * bf2f(u.y) + q2 * bf2f(u.z) + q3 * bf2f(u.w);
    d += __shfl_xor(d, 1);
    d += __shfl_xor(d, 2);
    d += __shfl_xor(d, 4);
    d += __shfl_xor(d, 8);
    if ((l & 15) == 0) sc[head][j] = d * 0.125f;  // 1/sqrt(64)
  }
  __syncthreads();

  // softmax over K=64, 16 threads per head (head = t>>4)
  {
    const int h = t >> 4;
    const int l2 = t & 15;
    float v0 = sc[h][l2], v1 = sc[h][l2 + 16], v2 = sc[h][l2 + 32],
          v3 = sc[h][l2 + 48];
    float m = fmaxf(fmaxf(v0, v1), fmaxf(v2, v3));
    m = fmaxf(m, __shfl_xor(m, 1));
    m = fmaxf(m, __shfl_xor(m, 2));
    m = fmaxf(m, __shfl_xor(m, 4));
    m = fmaxf(m, __shfl_xor(m, 8));
    v0 = __expf(v0 - m); v1 = __expf(v1 - m);
    v2 = __expf(v2 - m); v3 = __expf(v3 - m);
    float ss = v0 + v1 + v2 + v3;
    ss += __shfl_xor(ss, 1);
    ss += __shfl_xor(ss, 2);
    ss += __shfl_xor(ss, 4);
    ss += __shfl_xor(ss, 8);
    float inv = 1.0f / ss;
    sc[h][l2] = v0 * inv;
    sc[h][l2 + 16] = v1 * inv;
    sc[h][l2 + 32] = v2 * inv;
    sc[h][l2 + 48] = v3 * inv;
  }
  __syncthreads();

  // PV
  float a0 = 0.f, a1 = 0.f, a2 = 0.f, a3 = 0.f;
  for (int j = 0; j < K_; ++j) {
    const int r = rts[j];
    const size_t vb = ((size_t)(b * S_ + r)) * 3072 + 2048 + colo;
    ushort4 u = *(const ushort4*)&qkv[vb];
    float p = sc[head][j];
    a0 += p * bf2f(u.x);
    a1 += p * bf2f(u.y);
    a2 += p * bf2f(u.z);
    a3 += p * bf2f(u.w);
  }
  ushort4 o;
  o.x = f2bf(a0); o.y = f2bf(a1); o.z = f2bf(a2); o.w = f2bf(a3);
  *(ushort4*)&outp[(size_t)bs * D_ + colo] = o;
}

extern "C" void kernel_launch(void* const* d_in, const int* in_sizes, int n_in,
                              void* d_out, int out_size, void* d_ws,
                              size_t ws_size, hipStream_t stream) {
  const float* x = (const float*)d_in[0];
  const float* Wqkv = (const float*)d_in[1];
  const float* bqkv = (const float*)d_in[2];
  const float* Wproj = (const float*)d_in[3];
  const float* bproj = (const float*)d_in[4];
  const int* routes = (const int*)d_in[5];
  float* out = (float*)d_out;

  char* ws = (char*)d_ws;
  // ws layout (bytes):
  unsigned short* x_bf = (unsigned short*)(ws);                    //  8,388,608
  unsigned short* wqkvT = (unsigned short*)(ws + 8388608);         //  6,291,456
  unsigned short* wprojT = (unsigned short*)(ws + 14680064);       //  2,097,152
  unsigned short* qkv = (unsigned short*)(ws + 16777216);          // 25,165,824
  unsigned short* aout = (unsigned short*)(ws + 41943040);         //  8,388,608
  // total 50,331,648 bytes

  // 1) cast x to bf16
  {
    int n4 = (B_ * S_ * D_) / 4;  // 1,048,576
    cast_f32_bf16<<<n4 / 256, 256, 0, stream>>>((const float4*)x,
                                                (ushort4*)x_bf, n4);
  }
  // 2) transpose+cast weights
  transpose_cast<<<dim3(3 * D_ / 64, D_ / 64), 256, 0, stream>>>(Wqkv, wqkvT,
                                                                 D_, 3 * D_);
  transpose_cast<<<dim3(D_ / 64, D_ / 64), 256, 0, stream>>>(Wproj, wprojT, D_,
                                                             D_);
  // 3) qkv = x @ Wqkv + b  (bf16 out)
  gemm_bias<false><<<dim3(3 * D_ / 128, B_ * S_ / 128), 256, 0, stream>>>(
      x_bf, wqkvT, bqkv, qkv, B_ * S_, 3 * D_, D_);
  // 4) attention
  attn_kernel<<<B_ * S_, 256, 0, stream>>>(qkv, routes, aout);
  // 5) out = aout @ Wproj + b  (fp32 out)
  gemm_bias<true><<<dim3(D_ / 128, B_ * S_ / 128), 256, 0, stream>>>(
      aout, wprojT, bproj, out, B_ * S_, D_, D_);
}

// Round 2
// 146.760 us; speedup vs baseline: 1.2492x; 1.2492x over previous
//
#include <hip/hip_runtime.h>
#include <stdint.h>

#define B_ 2
#define S_ 2048
#define D_ 1024
#define H_ 16
#define HD_ 64
#define K_ 64

typedef __attribute__((ext_vector_type(8))) __bf16 bf16x8v;
typedef __attribute__((ext_vector_type(4))) float f32x4;
typedef __attribute__((ext_vector_type(8))) unsigned short ushort8v;

#define GLD_LDS16(g, l)                                                        \
  __builtin_amdgcn_global_load_lds(                                            \
      (const __attribute__((address_space(1))) void*)(g),                      \
      (__attribute__((address_space(3))) void*)(l), 16, 0, 0)

__device__ __forceinline__ float bf2f(unsigned short u) {
  union { unsigned u32; float f; } c;
  c.u32 = ((unsigned)u) << 16;
  return c.f;
}
__device__ __forceinline__ unsigned short f2bf(float f) {
  union { float f; unsigned u; } c;
  c.f = f;
  unsigned u = c.u;
  u += 0x7fffu + ((u >> 16) & 1u);  // RNE (finite inputs)
  return (unsigned short)(u >> 16);
}

// ---------------- cast x (fp32 -> bf16), vectorized ----------------
__global__ __launch_bounds__(256) void cast_f32_bf16(
    const float4* __restrict__ in, ushort4* __restrict__ outp, int n4) {
  int i = blockIdx.x * 256 + threadIdx.x;
  if (i >= n4) return;
  float4 v = in[i];
  ushort4 o;
  o.x = f2bf(v.x); o.y = f2bf(v.y); o.z = f2bf(v.z); o.w = f2bf(v.w);
  outp[i] = o;
}

// ------------- transpose + cast weights: W (R x C) -> WT (C x R) bf16 -------------
__global__ __launch_bounds__(256) void transpose_cast(
    const float* __restrict__ W, unsigned short* __restrict__ WT, int R, int C) {
  __shared__ float tile[64][65];
  const int r0 = blockIdx.y * 64;
  const int c0 = blockIdx.x * 64;
  const int t = threadIdx.x;
#pragma unroll
  for (int i = 0; i < 16; ++i) {
    int idx = t + i * 256;
    int rr = idx >> 6, cc = idx & 63;
    tile[rr][cc] = W[(size_t)(r0 + rr) * C + c0 + cc];
  }
  __syncthreads();
#pragma unroll
  for (int i = 0; i < 16; ++i) {
    int idx = t + i * 256;
    int rr = idx >> 6, cc = idx & 63;  // rr: row of WT (= col of W)
    WT[(size_t)(c0 + rr) * R + r0 + cc] = f2bf(tile[cc][rr]);
  }
}

// ---------------- bf16 GEMM, 128x128 tile, m97 structure ----------------
template <bool OUT_F32>
__global__ __launch_bounds__(256) void gemm_bias(
    const unsigned short* __restrict__ A, const unsigned short* __restrict__ Bt,
    const float* __restrict__ bias, void* __restrict__ Cout,
    int M, int N, int Kd) {
  __shared__ unsigned short As[128 * 32];
  __shared__ unsigned short Bs[128 * 32];
  const int t = threadIdx.x;
  const int w = t >> 6;
  const int l = t & 63;
  const int m0 = blockIdx.y * 128;
  const int n0 = blockIdx.x * 128;
  const int wr = w >> 1, wc = w & 1;

  f32x4 acc[4][4] = {};

  const int srow = t >> 2;          // 0..63
  const int scol = (t & 3) * 8;     // 0,8,16,24
  char* asBase = (char*)As + w * 1024;
  char* bsBase = (char*)Bs + w * 1024;

  const int lr = l & 15;
  const int kh = (l >> 4) * 8;

  const int KT = Kd >> 5;
  for (int kt = 0; kt < KT; ++kt) {
    const int k0 = kt << 5;
    {
      const unsigned short* g0 = A + (size_t)(m0 + srow) * Kd + k0 + scol;
      const unsigned short* g1 = A + (size_t)(m0 + 64 + srow) * Kd + k0 + scol;
      GLD_LDS16(g0, asBase);
      GLD_LDS16(g1, asBase + 4096);
      const unsigned short* h0 = Bt + (size_t)(n0 + srow) * Kd + k0 + scol;
      const unsigned short* h1 = Bt + (size_t)(n0 + 64 + srow) * Kd + k0 + scol;
      GLD_LDS16(h0, bsBase);
      GLD_LDS16(h1, bsBase + 4096);
    }
    __syncthreads();
    bf16x8v af[4], bfv[4];
#pragma unroll
    for (int m = 0; m < 4; ++m)
      af[m] = *(const bf16x8v*)&As[(wr * 64 + m * 16 + lr) * 32 + kh];
#pragma unroll
    for (int n = 0; n < 4; ++n)
      bfv[n] = *(const bf16x8v*)&Bs[(wc * 64 + n * 16 + lr) * 32 + kh];
#pragma unroll
    for (int m = 0; m < 4; ++m)
#pragma unroll
      for (int n = 0; n < 4; ++n)
        acc[m][n] = __builtin_amdgcn_mfma_f32_16x16x32_bf16(af[m], bfv[n],
                                                            acc[m][n], 0, 0, 0);
    __syncthreads();
  }

  const int rbase = (l >> 4) * 4;
#pragma unroll
  for (int m = 0; m < 4; ++m) {
#pragma unroll
    for (int n = 0; n < 4; ++n) {
      const int gc = n0 + wc * 64 + n * 16 + lr;
      const float bv = bias[gc];
#pragma unroll
      for (int j = 0; j < 4; ++j) {
        const int gr = m0 + wr * 64 + m * 16 + rbase + j;
        float v = acc[m][n][j] + bv;
        if (OUT_F32)
          ((float*)Cout)[(size_t)gr * N + gc] = v;
        else
          ((unsigned short*)Cout)[(size_t)gr * N + gc] = f2bf(v);
      }
    }
  }
}

// ---------------- routed gather attention (v2) ----------------
// qkv: (B*S) x 3072 bf16 bits, layout [q(1024)|k(1024)|v(1024)]
// one block per (b,s); wave w: key-half kh2=w>>1 (32 keys), head-half hh=w&1
// (heads 8*hh..8*hh+7). lane l covers dims [hh*512 + l*8, +8) -> 16B loads,
// 8 lanes per head, 3-step shfl reduce.
__global__ __launch_bounds__(256) void attn_kernel(
    const unsigned short* __restrict__ qkv, const int* __restrict__ routes,
    unsigned short* __restrict__ outp) {
  __shared__ float sc[16][68];       // padded: bank = (4*head + j) % 32
  __shared__ unsigned rtsoff[64];    // precomputed (b*S + r) * 3072
  __shared__ float pbuf[1024];       // cross-wave PV partials
  const int bs = blockIdx.x;
  const int b = bs >> 11;            // / S_
  const int s = bs & (S_ - 1);
  const int t = threadIdx.x;
  const int w = t >> 6, l = t & 63;
  const int kh2 = w >> 1, hh = w & 1;

  if (t < 64) {
    int r = routes[s * K_ + t];
    r = min(max(r, 0), S_ - 1);
    rtsoff[t] = (unsigned)(b * S_ + r) * 3072u;
  }
  __syncthreads();

  const unsigned colo = hh * 512 + l * 8;
  const int head = colo >> 6;
  const size_t rowbase = (size_t)bs * 3072;

  float q[8];
  {
    ushort8v u = *(const ushort8v*)(qkv + rowbase + colo);
#pragma unroll
    for (int i = 0; i < 8; ++i) q[i] = bf2f(u[i]) * 0.125f;  // 1/sqrt(64)
  }

  const unsigned kofs = 1024u + colo;
  const unsigned vofs = 2048u + colo;
  const int jbase = kh2 * 32;

  // scores
#pragma unroll 4
  for (int j2 = 0; j2 < 32; ++j2) {
    const int j = jbase + j2;
    ushort8v u = *(const ushort8v*)(qkv + (rtsoff[j] + kofs));
    float d = q[0] * bf2f(u[0]);
#pragma unroll
    for (int i = 1; i < 8; ++i) d += q[i] * bf2f(u[i]);
    d += __shfl_xor(d, 1);
    d += __shfl_xor(d, 2);
    d += __shfl_xor(d, 4);
    if ((l & 7) == 0) sc[head][j] = d;
  }
  __syncthreads();

  // softmax over K=64, 16 threads per head
  {
    const int h = t >> 4;
    const int l2 = t & 15;
    float v0 = sc[h][l2], v1 = sc[h][l2 + 16], v2 = sc[h][l2 + 32],
          v3 = sc[h][l2 + 48];
    float m = fmaxf(fmaxf(v0, v1), fmaxf(v2, v3));
    m = fmaxf(m, __shfl_xor(m, 1));
    m = fmaxf(m, __shfl_xor(m, 2));
    m = fmaxf(m, __shfl_xor(m, 4));
    m = fmaxf(m, __shfl_xor(m, 8));
    v0 = __expf(v0 - m); v1 = __expf(v1 - m);
    v2 = __expf(v2 - m); v3 = __expf(v3 - m);
    float ss = v0 + v1 + v2 + v3;
    ss += __shfl_xor(ss, 1);
    ss += __shfl_xor(ss, 2);
    ss += __shfl_xor(ss, 4);
    ss += __shfl_xor(ss, 8);
    float inv = 1.0f / ss;
    sc[h][l2] = v0 * inv;
    sc[h][l2 + 16] = v1 * inv;
    sc[h][l2 + 32] = v2 * inv;
    sc[h][l2 + 48] = v3 * inv;
  }
  __syncthreads();

  // PV
  float acc[8] = {};
#pragma unroll 4
  for (int j2 = 0; j2 < 32; ++j2) {
    const int j = jbase + j2;
    ushort8v u = *(const ushort8v*)(qkv + (rtsoff[j] + vofs));
    const float p = sc[head][j];
#pragma unroll
    for (int i = 0; i < 8; ++i) acc[i] += p * bf2f(u[i]);
  }

  if (kh2 == 1) {
    f32x4 a0 = {acc[0], acc[1], acc[2], acc[3]};
    f32x4 a1 = {acc[4], acc[5], acc[6], acc[7]};
    *(f32x4*)&pbuf[colo] = a0;
    *(f32x4*)&pbuf[colo + 4] = a1;
  }
  __syncthreads();
  if (kh2 == 0) {
    ushort8v o;
#pragma unroll
    for (int i = 0; i < 8; ++i) o[i] = f2bf(acc[i] + pbuf[colo + i]);
    *(ushort8v*)(outp + (size_t)bs * D_ + colo) = o;
  }
}

extern "C" void kernel_launch(void* const* d_in, const int* in_sizes, int n_in,
                              void* d_out, int out_size, void* d_ws,
                              size_t ws_size, hipStream_t stream) {
  const float* x = (const float*)d_in[0];
  const float* Wqkv = (const float*)d_in[1];
  const float* bqkv = (const float*)d_in[2];
  const float* Wproj = (const float*)d_in[3];
  const float* bproj = (const float*)d_in[4];
  const int* routes = (const int*)d_in[5];
  float* out = (float*)d_out;

  char* ws = (char*)d_ws;
  unsigned short* x_bf = (unsigned short*)(ws);                    //  8,388,608
  unsigned short* wqkvT = (unsigned short*)(ws + 8388608);         //  6,291,456
  unsigned short* wprojT = (unsigned short*)(ws + 14680064);       //  2,097,152
  unsigned short* qkv = (unsigned short*)(ws + 16777216);          // 25,165,824
  unsigned short* aout = (unsigned short*)(ws + 41943040);         //  8,388,608

  {
    int n4 = (B_ * S_ * D_) / 4;
    cast_f32_bf16<<<n4 / 256, 256, 0, stream>>>((const float4*)x,
                                                (ushort4*)x_bf, n4);
  }
  transpose_cast<<<dim3(3 * D_ / 64, D_ / 64), 256, 0, stream>>>(Wqkv, wqkvT,
                                                                 D_, 3 * D_);
  transpose_cast<<<dim3(D_ / 64, D_ / 64), 256, 0, stream>>>(Wproj, wprojT, D_,
                                                             D_);
  gemm_bias<false><<<dim3(3 * D_ / 128, B_ * S_ / 128), 256, 0, stream>>>(
      x_bf, wqkvT, bqkv, qkv, B_ * S_, 3 * D_, D_);
  attn_kernel<<<B_ * S_, 256, 0, stream>>>(qkv, routes, aout);
  gemm_bias<true><<<dim3(D_ / 128, B_ * S_ / 128), 256, 0, stream>>>(
      aout, wprojT, bproj, out, B_ * S_, D_, D_);
}